// Round 8
// baseline (235.188 us; speedup 1.0000x reference)
//
#include <hip/hip_runtime.h>
#include <hip/hip_bf16.h>

#define N_NODES 50000
#define N_EDGES 800000
#define N_FEAT  64
#define UNITS   128
#define OUT_C   256
#define MAXDEG  64
#define NPART   8          // one partition per XCD
#define ROWS_PER_PART 6250 // 50000 / 8

// ---------------------------------------------------------------------------
// Kernel 0: detect int64 vs int32 edge_index (odd words all zero => int64).
// ---------------------------------------------------------------------------
__global__ void detect_idx_dtype(const void* __restrict__ ei_raw,
                                 int* __restrict__ flag)
{
    const int* p = (const int*)ei_raw;
    int v = p[2 * threadIdx.x + 1];
    unsigned long long b = __ballot(v == 0);
    if (threadIdx.x == 0) *flag = (b == ~0ull) ? 1 : 0;
}

// ---------------------------------------------------------------------------
// Kernel 1: XCD-partitioned bucket fill (round-5/7 win: pins adj/cursor
// lines to one XCD's L2; WRITE_SIZE 44.5MB -> ~10MB, dur 60 -> <43us).
// Partition = blockIdx.x & 7 under round-robin block->XCD dispatch.
// ---------------------------------------------------------------------------
__global__ __launch_bounds__(256) void bucket_fill(
    const void* __restrict__ ei_raw, const int* __restrict__ flag,
    int* __restrict__ cursor, unsigned short* __restrict__ adj)
{
    int my_p  = blockIdx.x & (NPART - 1);
    int chunk = blockIdx.x >> 3;
    int e = chunk * 256 + threadIdx.x;
    if (e >= N_EDGES) return;

    int is64 = *flag;
    int row;
    if (is64) row = (int)((const long long*)ei_raw)[e];
    else      row = ((const int*)ei_raw)[e];
    row = min(max(row, 0), N_NODES - 1);

    if (row / ROWS_PER_PART != my_p) return;

    int col;
    if (is64) col = (int)((const long long*)ei_raw)[(long long)N_EDGES + e];
    else      col = ((const int*)ei_raw)[N_EDGES + e];
    col = min(max(col, 0), N_NODES - 1);

    int pos = atomicAdd(&cursor[row], 1);
    if (pos < MAXDEG) adj[row * MAXDEG + pos] = (unsigned short)col;
}

// ---------------------------------------------------------------------------
// Kernel 2: fused gather-mean + half-GEMM [64 rows] x [64][128] + bias+relu.
// blockIdx.y = 0: (gathered neighbor mean) @ wn -> out cols 0..127
// blockIdx.y = 1: x @ wsf -> out cols 128..255
// 256 threads. Half-0 blocks build the A-tile by gathering/averaging
// neighbor rows in-kernel (wave per 16 rows, lane = feature) -- this
// removes the 25.6MB mean round-trip and the separate aggregate launch.
// GEMM: thread (cg=t&31 -> 4 cols, r0=(t>>5)*8 -> 8 rows), 32 FMA per
// 9 LDS reads per k. LDS 48KB (W 32KB + A 16KB) -> 3 blocks/CU.
// unroll-4 only + named float4s (rounds 3/4 post-mortem: full unroll or
// addressed register arrays => 800MB scratch traffic).
// ---------------------------------------------------------------------------
#define FMA4(ACC, AV, W) \
    ACC.x += (AV) * (W).x; ACC.y += (AV) * (W).y; \
    ACC.z += (AV) * (W).z; ACC.w += (AV) * (W).w;

#define G_ROWS 64

__global__ __launch_bounds__(256, 3) void fused_gemm(
    const float* __restrict__ x,        // [N][64]
    const int* __restrict__ cursor,     // [N] degrees
    const unsigned short* __restrict__ adj,  // [N][MAXDEG]
    const float* __restrict__ wn,       // [64][128]
    const float* __restrict__ wsf,      // [64][128]
    const float* __restrict__ bias,     // [256]
    float* __restrict__ out)            // [N][256]
{
    __shared__ float W[N_FEAT * UNITS];   // 32 KB
    __shared__ float A[G_ROWS * N_FEAT];  // 16 KB

    const int t = threadIdx.x;
    const int half = blockIdx.y;
    const int row0 = blockIdx.x * G_ROWS;
    const float* __restrict__ wsrc = half ? wsf : wn;

    // Stage W: 2048 float4 total, 8 per thread, coalesced.
    {
        const float4* w4 = (const float4*)wsrc;
        float4* W4s = (float4*)W;
        #pragma unroll
        for (int i = 0; i < 8; ++i) W4s[t + 256 * i] = w4[t + 256 * i];
    }

    if (half) {
        // Stage A = x rows: 1024 float4 total, 4 per thread.
        float4* A4 = (float4*)A;
        #pragma unroll
        for (int i = 0; i < 4; ++i) {
            int idx = t + 256 * i;
            int r = idx >> 4, k4 = idx & 15;
            int grow = row0 + r;
            float4 v = make_float4(0.f, 0.f, 0.f, 0.f);
            if (grow < N_NODES) v = *(const float4*)&x[grow * N_FEAT + k4 * 4];
            A4[idx] = v;
        }
    } else {
        // Stage A = neighbor mean, gathered in-kernel.
        // Wave w handles rows [w*16, w*16+16); lane = feature.
        int wave = t >> 6, lane = t & 63;
        for (int i = 0; i < 16; ++i) {
            int r = wave * 16 + i;
            int grow = row0 + r;
            int deg = 0;
            if (grow < N_NODES) deg = min(cursor[grow], MAXDEG);
            const unsigned short* a = &adj[grow * MAXDEG];

            float s0 = 0.f, s1 = 0.f, s2 = 0.f, s3 = 0.f;
            int j = 0;
            for (; j + 4 <= deg; j += 4) {
                ushort4 n = *(const ushort4*)&a[j];   // wave-uniform 8B load
                float v0 = x[(int)n.x * N_FEAT + lane];
                float v1 = x[(int)n.y * N_FEAT + lane];
                float v2 = x[(int)n.z * N_FEAT + lane];
                float v3 = x[(int)n.w * N_FEAT + lane];
                s0 += v0; s1 += v1; s2 += v2; s3 += v3;
            }
            for (; j < deg; ++j) s0 += x[(int)a[j] * N_FEAT + lane];
            float s = (s0 + s1) + (s2 + s3);
            A[r * N_FEAT + lane] = s / fmaxf((float)deg, 1.0f);
        }
    }
    __syncthreads();

    const int cg = t & 31;            // cols [cg*4, cg*4+4)
    const int r0 = (t >> 5) * 8;      // rows [r0, r0+8)
    const float4* W4 = (const float4*)W;   // [64 k][32 colgrp]

    float4 acc0 = make_float4(0.f, 0.f, 0.f, 0.f);
    float4 acc1 = acc0, acc2 = acc0, acc3 = acc0;
    float4 acc4 = acc0, acc5 = acc0, acc6 = acc0, acc7 = acc0;

    #pragma unroll 4
    for (int k = 0; k < N_FEAT; ++k) {
        float4 w = W4[k * 32 + cg];           // half-wave b128, conflict-free
        float a0 = A[(r0 + 0) * N_FEAT + k];  // 2-addr broadcast b32
        float a1 = A[(r0 + 1) * N_FEAT + k];
        float a2 = A[(r0 + 2) * N_FEAT + k];
        float a3 = A[(r0 + 3) * N_FEAT + k];
        float a4 = A[(r0 + 4) * N_FEAT + k];
        float a5 = A[(r0 + 5) * N_FEAT + k];
        float a6 = A[(r0 + 6) * N_FEAT + k];
        float a7 = A[(r0 + 7) * N_FEAT + k];
        FMA4(acc0, a0, w)
        FMA4(acc1, a1, w)
        FMA4(acc2, a2, w)
        FMA4(acc3, a3, w)
        FMA4(acc4, a4, w)
        FMA4(acc5, a5, w)
        FMA4(acc6, a6, w)
        FMA4(acc7, a7, w)
    }

    const int cbase = half * UNITS + cg * 4;
    float4 b = *(const float4*)&bias[cbase];

#define STORE_ROW(ACC, RI) { \
        int grow = row0 + r0 + (RI); \
        if (grow < N_NODES) { \
            float4 o; \
            o.x = fmaxf(ACC.x + b.x, 0.f); o.y = fmaxf(ACC.y + b.y, 0.f); \
            o.z = fmaxf(ACC.z + b.z, 0.f); o.w = fmaxf(ACC.w + b.w, 0.f); \
            *(float4*)&out[(long long)grow * OUT_C + cbase] = o; \
        } }

    STORE_ROW(acc0, 0)
    STORE_ROW(acc1, 1)
    STORE_ROW(acc2, 2)
    STORE_ROW(acc3, 3)
    STORE_ROW(acc4, 4)
    STORE_ROW(acc5, 5)
    STORE_ROW(acc6, 6)
    STORE_ROW(acc7, 7)
#undef STORE_ROW
}

// ---------------------------------------------------------------------------
extern "C" void kernel_launch(void* const* d_in, const int* in_sizes, int n_in,
                              void* d_out, int out_size, void* d_ws, size_t ws_size,
                              hipStream_t stream) {
    const float* x    = (const float*)d_in[0];
    const void*  ei   = d_in[1];                 // int64 or int32 [2][E]
    const float* wn   = (const float*)d_in[2];
    const float* wsf  = (const float*)d_in[3];
    const float* bias = (const float*)d_in[4];
    float*       out  = (float*)d_out;

    // Workspace (~6.6 MB): adj u16[50000*64] | cursor i32[50000] | flag i32.
    unsigned short* adj    = (unsigned short*)d_ws;
    int*            cursor = (int*)(adj + (size_t)N_NODES * MAXDEG);
    int*            flag   = cursor + N_NODES;

    hipMemsetAsync(cursor, 0, (size_t)N_NODES * sizeof(int), stream);
    detect_idx_dtype<<<1, 64, 0, stream>>>(ei, flag);

    // Partitioned fill: 3125 chunks x 8 partitions.
    int eblocks = (N_EDGES + 255) / 256;                 // 3125
    bucket_fill<<<eblocks * NPART, 256, 0, stream>>>(ei, flag, cursor, adj);

    // Fused gather-mean + dual half-GEMM + bias + relu.
    dim3 ggrid((N_NODES + G_ROWS - 1) / G_ROWS, 2);      // (782, 2)
    fused_gemm<<<ggrid, 256, 0, stream>>>(x, cursor, adj, wn, wsf, bias, out);
}

// Round 10
// 183.425 us; speedup vs baseline: 1.2822x; 1.2822x over previous
//
#include <hip/hip_runtime.h>
#include <hip/hip_bf16.h>

#define N_NODES 50000
#define N_EDGES 800000
#define N_FEAT  64
#define UNITS   128
#define OUT_C   256
#define MAXDEG  64
#define NPART   8          // one partition per XCD
#define ROWS_PER_PART 6250 // 50000 / 8

// ---------------------------------------------------------------------------
// Kernel 0: detect int64 vs int32 edge_index (odd words all zero => int64).
// ---------------------------------------------------------------------------
__global__ void detect_idx_dtype(const void* __restrict__ ei_raw,
                                 int* __restrict__ flag)
{
    const int* p = (const int*)ei_raw;
    int v = p[2 * threadIdx.x + 1];
    unsigned long long b = __ballot(v == 0);
    if (threadIdx.x == 0) *flag = (b == ~0ull) ? 1 : 0;
}

// ---------------------------------------------------------------------------
// Kernel 1: XCD-partitioned bucket fill (round-7 win: pins adj/cursor lines
// to one XCD's L2). Partition = blockIdx.x & 7 under round-robin dispatch.
// ---------------------------------------------------------------------------
__global__ __launch_bounds__(256) void bucket_fill(
    const void* __restrict__ ei_raw, const int* __restrict__ flag,
    int* __restrict__ cursor, unsigned short* __restrict__ adj)
{
    int my_p  = blockIdx.x & (NPART - 1);
    int chunk = blockIdx.x >> 3;
    int e = chunk * 256 + threadIdx.x;
    if (e >= N_EDGES) return;

    int is64 = *flag;
    int row;
    if (is64) row = (int)((const long long*)ei_raw)[e];
    else      row = ((const int*)ei_raw)[e];
    row = min(max(row, 0), N_NODES - 1);

    if (row / ROWS_PER_PART != my_p) return;

    int col;
    if (is64) col = (int)((const long long*)ei_raw)[(long long)N_EDGES + e];
    else      col = ((const int*)ei_raw)[N_EDGES + e];
    col = min(max(col, 0), N_NODES - 1);

    int pos = atomicAdd(&cursor[row], 1);
    if (pos < MAXDEG) adj[row * MAXDEG + pos] = (unsigned short)col;
}

// ---------------------------------------------------------------------------
// Kernel 2: gather-aggregate (separate kernel -- round-8 fusion post-mortem:
// 50000 independent waves are what hides gather latency).
// Wave per node, lane = feature, 8-deep load ILP.
// ---------------------------------------------------------------------------
__global__ __launch_bounds__(256) void aggregate(
    const float* __restrict__ x, const int* __restrict__ cursor,
    const unsigned short* __restrict__ adj, float* __restrict__ mean)
{
    int wv   = (blockIdx.x * blockDim.x + threadIdx.x) >> 6;
    int lane = threadIdx.x & 63;
    if (wv >= N_NODES) return;
    int deg = min(cursor[wv], MAXDEG);
    const unsigned short* a = &adj[wv * MAXDEG];

    float s0 = 0.f, s1 = 0.f, s2 = 0.f, s3 = 0.f;
    int j = 0;
    for (; j + 8 <= deg; j += 8) {
        ushort4 n0 = *(const ushort4*)&a[j];
        ushort4 n1 = *(const ushort4*)&a[j + 4];
        float v0 = x[(int)n0.x * N_FEAT + lane];
        float v1 = x[(int)n0.y * N_FEAT + lane];
        float v2 = x[(int)n0.z * N_FEAT + lane];
        float v3 = x[(int)n0.w * N_FEAT + lane];
        float v4 = x[(int)n1.x * N_FEAT + lane];
        float v5 = x[(int)n1.y * N_FEAT + lane];
        float v6 = x[(int)n1.z * N_FEAT + lane];
        float v7 = x[(int)n1.w * N_FEAT + lane];
        s0 += v0; s1 += v1; s2 += v2; s3 += v3;
        s0 += v4; s1 += v5; s2 += v6; s3 += v7;
    }
    for (; j + 4 <= deg; j += 4) {
        ushort4 n = *(const ushort4*)&a[j];
        float v0 = x[(int)n.x * N_FEAT + lane];
        float v1 = x[(int)n.y * N_FEAT + lane];
        float v2 = x[(int)n.z * N_FEAT + lane];
        float v3 = x[(int)n.w * N_FEAT + lane];
        s0 += v0; s1 += v1; s2 += v2; s3 += v3;
    }
    for (; j < deg; ++j) s0 += x[(int)a[j] * N_FEAT + lane];
    float s = (s0 + s1) + (s2 + s3);
    mean[wv * N_FEAT + lane] = s / fmaxf((float)deg, 1.0f);
}

// ---------------------------------------------------------------------------
// Kernel 3: half-GEMM [128 rows] x [64][128] + bias + relu.
// Round-7 post-mortem: old gemm was LDS-throughput-bound (35 LDS-cyc per
// 32 VALU-cyc per wave-k, LDS shared by 4 SIMDs => ~38us). This version:
//  - A in LDS, read as b128 (4 k per read), XOR-swizzled (k4 ^= r>>3).
//  - W NOT in LDS: global reads, 32KB L1-resident, separate pipe.
//  - 8 rows x 8 cols per thread: 256 FMA per 8 LDS-b128 per 4k.
// All named float4s, outer loop unroll 1 (rounds-3/4 spill lesson).
// ---------------------------------------------------------------------------
#define FMA4(ACC, AV, W) \
    ACC.x += (AV) * (W).x; ACC.y += (AV) * (W).y; \
    ACC.z += (AV) * (W).z; ACC.w += (AV) * (W).w;

#define G_ROWS 128

__global__ __launch_bounds__(256, 3) void half_gemm(
    const float* __restrict__ mean,   // [N][64]
    const float* __restrict__ x,      // [N][64]
    const float* __restrict__ wn,     // [64][128]
    const float* __restrict__ wsf,    // [64][128]
    const float* __restrict__ bias,   // [256]
    float* __restrict__ out)          // [N][256]
{
    __shared__ float4 A4[G_ROWS * 16];    // 32 KB, k4 XOR-swizzled by r>>3

    const int t = threadIdx.x;
    const int half = blockIdx.y;
    const int row0 = blockIdx.x * G_ROWS;
    const float* __restrict__ src  = half ? x   : mean;
    const float* __restrict__ wsrc = half ? wsf : wn;

    // Stage A: 2048 float4, 8 per thread, coalesced; swizzled store.
    #pragma unroll
    for (int i = 0; i < 8; ++i) {
        int idx = t + 256 * i;
        int r = idx >> 4, k4 = idx & 15;
        int grow = row0 + r;
        float4 v = make_float4(0.f, 0.f, 0.f, 0.f);
        if (grow < N_NODES) v = *(const float4*)&src[grow * N_FEAT + k4 * 4];
        A4[(r << 4) | (k4 ^ (r >> 3))] = v;
    }
    __syncthreads();

    const int cg = t & 15;            // cols [cg*8, cg*8+8)
    const int rg = t >> 4;            // rows [rg*8, rg*8+8)
    const int c0 = cg * 8;
    const int r0 = rg * 8;
    const int sw = rg;                // (r0+i)>>3 == rg for i in [0,8)

    float4 z = make_float4(0.f, 0.f, 0.f, 0.f);
    float4 acc0A = z, acc0B = z, acc1A = z, acc1B = z;
    float4 acc2A = z, acc2B = z, acc3A = z, acc3B = z;
    float4 acc4A = z, acc4B = z, acc5A = z, acc5B = z;
    float4 acc6A = z, acc6B = z, acc7A = z, acc7B = z;

#define STEP(COMP, J) { \
        float4 wA = *(const float4*)&wsrc[(kk * 4 + (J)) * UNITS + c0]; \
        float4 wB = *(const float4*)&wsrc[(kk * 4 + (J)) * UNITS + c0 + 4]; \
        FMA4(acc0A, a0.COMP, wA) FMA4(acc0B, a0.COMP, wB) \
        FMA4(acc1A, a1.COMP, wA) FMA4(acc1B, a1.COMP, wB) \
        FMA4(acc2A, a2.COMP, wA) FMA4(acc2B, a2.COMP, wB) \
        FMA4(acc3A, a3.COMP, wA) FMA4(acc3B, a3.COMP, wB) \
        FMA4(acc4A, a4.COMP, wA) FMA4(acc4B, a4.COMP, wB) \
        FMA4(acc5A, a5.COMP, wA) FMA4(acc5B, a5.COMP, wB) \
        FMA4(acc6A, a6.COMP, wA) FMA4(acc6B, a6.COMP, wB) \
        FMA4(acc7A, a7.COMP, wA) FMA4(acc7B, a7.COMP, wB) }

    #pragma unroll 1
    for (int kk = 0; kk < 16; ++kk) {
        int ks = kk ^ sw;
        float4 a0 = A4[((r0 + 0) << 4) | ks];
        float4 a1 = A4[((r0 + 1) << 4) | ks];
        float4 a2 = A4[((r0 + 2) << 4) | ks];
        float4 a3 = A4[((r0 + 3) << 4) | ks];
        float4 a4 = A4[((r0 + 4) << 4) | ks];
        float4 a5 = A4[((r0 + 5) << 4) | ks];
        float4 a6 = A4[((r0 + 6) << 4) | ks];
        float4 a7 = A4[((r0 + 7) << 4) | ks];
        STEP(x, 0)
        STEP(y, 1)
        STEP(z, 2)
        STEP(w, 3)
    }
#undef STEP

    const int cbase = half * UNITS + c0;
    float4 bA = *(const float4*)&bias[cbase];
    float4 bB = *(const float4*)&bias[cbase + 4];

#define STORE_ROW(ACA, ACB, RI) { \
        int grow = row0 + r0 + (RI); \
        if (grow < N_NODES) { \
            float4 o; \
            o.x = fmaxf(ACA.x + bA.x, 0.f); o.y = fmaxf(ACA.y + bA.y, 0.f); \
            o.z = fmaxf(ACA.z + bA.z, 0.f); o.w = fmaxf(ACA.w + bA.w, 0.f); \
            *(float4*)&out[(long long)grow * OUT_C + cbase] = o; \
            o.x = fmaxf(ACB.x + bB.x, 0.f); o.y = fmaxf(ACB.y + bB.y, 0.f); \
            o.z = fmaxf(ACB.z + bB.z, 0.f); o.w = fmaxf(ACB.w + bB.w, 0.f); \
            *(float4*)&out[(long long)grow * OUT_C + cbase + 4] = o; \
        } }

    STORE_ROW(acc0A, acc0B, 0)
    STORE_ROW(acc1A, acc1B, 1)
    STORE_ROW(acc2A, acc2B, 2)
    STORE_ROW(acc3A, acc3B, 3)
    STORE_ROW(acc4A, acc4B, 4)
    STORE_ROW(acc5A, acc5B, 5)
    STORE_ROW(acc6A, acc6B, 6)
    STORE_ROW(acc7A, acc7B, 7)
#undef STORE_ROW
}

// ---------------------------------------------------------------------------
extern "C" void kernel_launch(void* const* d_in, const int* in_sizes, int n_in,
                              void* d_out, int out_size, void* d_ws, size_t ws_size,
                              hipStream_t stream) {
    const float* x    = (const float*)d_in[0];
    const void*  ei   = d_in[1];                 // int64 or int32 [2][E]
    const float* wn   = (const float*)d_in[2];
    const float* wsf  = (const float*)d_in[3];
    const float* bias = (const float*)d_in[4];
    float*       out  = (float*)d_out;

    // Workspace (~19.4 MB): mean f32[50000*64] | adj u16[50000*64] |
    // cursor i32[50000] | flag i32.
    float*          mean   = (float*)d_ws;
    unsigned short* adj    = (unsigned short*)(mean + (size_t)N_NODES * N_FEAT);
    int*            cursor = (int*)(adj + (size_t)N_NODES * MAXDEG);
    int*            flag   = cursor + N_NODES;

    hipMemsetAsync(cursor, 0, (size_t)N_NODES * sizeof(int), stream);
    detect_idx_dtype<<<1, 64, 0, stream>>>(ei, flag);

    // Partitioned fill: 3125 chunks x 8 partitions.
    int eblocks = (N_EDGES + 255) / 256;                 // 3125
    bucket_fill<<<eblocks * NPART, 256, 0, stream>>>(ei, flag, cursor, adj);

    int ablocks = (N_NODES * 64 + 255) / 256;            // 12500 (wave/node)
    aggregate<<<ablocks, 256, 0, stream>>>(x, cursor, adj, mean);

    dim3 ggrid((N_NODES + G_ROWS - 1) / G_ROWS, 2);      // (391, 2)
    half_gemm<<<ggrid, 256, 0, stream>>>(mean, x, wn, wsf, bias, out);
}